// Round 1
// baseline (1417.973 us; speedup 1.0000x reference)
//
#include <hip/hip_runtime.h>
#include <math.h>

#define NB   8
#define CIN  128
#define COUT 128
#define HH   64
#define WW   64
#define OMC  27      // 18 offset + 9 mask channels
#define CICH 8       // ci chunk
#define NKK  (CICH*9)  // 72
#define WPAD 132     // s_w row stride: 16B-aligned, breaks bank pathology

__global__ __launch_bounds__(256, 2)
void dcn_fused_kernel(const float* __restrict__ x,
                      const float* __restrict__ w_off,
                      const float* __restrict__ b_off,
                      const float* __restrict__ w_def,
                      const float* __restrict__ b_def,
                      float* __restrict__ out) {
  __shared__ float s_off[OMC * WW];    //  6912 B: offsets (raw) + masks (sigmoided)
  __shared__ float s_w[NKK * WPAD];    // 38016 B: w_def chunk, [kk][oc]
  __shared__ float s_samp[NKK * WW];   // 18432 B: modulated bilinear samples [kk][wo]

  const int t  = threadIdx.x;
  const int b  = blockIdx.x >> 6;
  const int ho = blockIdx.x & 63;
  const float* __restrict__ xb = x + (size_t)b * CIN * HH * WW;

  // ---------------- Stage A: 27-channel 3x3 offset conv for this row ----------------
  for (int f = t; f < OMC * WW; f += 256) {
    const int c = f >> 6;      // channel 0..26
    const int p = f & 63;      // wo
    float acc = b_off[c];
    const float* wc = w_off + c * (CIN * 9);
    for (int ci = 0; ci < CIN; ++ci) {
      const float* xci = xb + ci * (HH * WW);
      const float* wr  = wc + ci * 9;
      #pragma unroll
      for (int ky = 0; ky < 3; ++ky) {
        const int y = ho + ky - 1;
        if (y < 0 || y >= HH) continue;
        const float* xrow = xci + y * WW;
        #pragma unroll
        for (int kx = 0; kx < 3; ++kx) {
          const int xx = p + kx - 1;
          if (xx < 0 || xx >= WW) continue;
          acc = fmaf(xrow[xx], wr[ky * 3 + kx], acc);
        }
      }
    }
    if (c >= 18) acc = 1.0f / (1.0f + __expf(-acc));  // sigmoid for mask channels
    s_off[f] = acc;
  }
  __syncthreads();

  // ---------------- Stage B: deformable conv ----------------
  // Thread owns 8 output channels x 4 pixels.
  const int p0  = (t & 15) << 2;   // pixel base 0..60
  const int oc0 = (t >> 4) << 3;   // oc base 0..120
  float acc[8][4];
  #pragma unroll
  for (int i = 0; i < 8; ++i)
    #pragma unroll
    for (int j = 0; j < 4; ++j) acc[i][j] = 0.0f;

  for (int ci0 = 0; ci0 < CIN; ci0 += CICH) {
    // B1: stage w_def chunk transposed: s_w[kk][oc] = w_def[oc][ci0*9 + kk]
    // (kk = cc*9+k is contiguous in global memory for fixed oc)
    for (int f = t; f < COUT * NKK; f += 256) {
      const int oc = f / NKK;
      const int kk = f - oc * NKK;
      s_w[kk * WPAD + oc] = w_def[oc * (CIN * 9) + ci0 * 9 + kk];
    }

    // B2: modulated bilinear samples: s_samp[kk][p], kk = cc*9 + k
    for (int f = t; f < NKK * WW; f += 256) {   // 4608 = 18 * 256, no tail
      const int kk = f >> 6;
      const int p  = f & 63;
      const int cc = kk / 9;
      const int k  = kk - cc * 9;
      const int ky = k / 3;
      const int kx = k - ky * 3;
      const float offy = s_off[(2 * k)     * WW + p];
      const float offx = s_off[(2 * k + 1) * WW + p];
      const float m    = s_off[(18 + k)    * WW + p];
      const float py = offy + (float)(ho + ky - 1);
      const float px = offx + (float)(p  + kx - 1);
      const float y0f = floorf(py);
      const float x0f = floorf(px);
      const float wy = py - y0f;
      const float wx = px - x0f;
      const int y0 = (int)y0f;
      const int x0 = (int)x0f;
      const float* xc = xb + (ci0 + cc) * (HH * WW);
      const bool y0v = (y0 >= 0)     && (y0 < HH);
      const bool y1v = (y0 + 1 >= 0) && (y0 + 1 < HH);
      const bool x0v = (x0 >= 0)     && (x0 < WW);
      const bool x1v = (x0 + 1 >= 0) && (x0 + 1 < WW);
      float v00 = 0.f, v01 = 0.f, v10 = 0.f, v11 = 0.f;
      if (y0v && x0v) v00 = xc[y0 * WW + x0];
      if (y0v && x1v) v01 = xc[y0 * WW + x0 + 1];
      if (y1v && x0v) v10 = xc[(y0 + 1) * WW + x0];
      if (y1v && x1v) v11 = xc[(y0 + 1) * WW + x0 + 1];
      const float s = (v00 * (1.f - wx) + v01 * wx) * (1.f - wy) +
                      (v10 * (1.f - wx) + v11 * wx) * wy;
      s_samp[f] = s * m;
    }
    __syncthreads();

    // B3: register-blocked GEMM: acc[oc][pix] += w[oc][kk] * samp[kk][pix]
    for (int kk = 0; kk < NKK; ++kk) {
      const float4 sv = *(const float4*)&s_samp[kk * WW + p0];
      const float4 wa = *(const float4*)&s_w[kk * WPAD + oc0];
      const float4 wb = *(const float4*)&s_w[kk * WPAD + oc0 + 4];
      const float wv[8]  = {wa.x, wa.y, wa.z, wa.w, wb.x, wb.y, wb.z, wb.w};
      const float svv[4] = {sv.x, sv.y, sv.z, sv.w};
      #pragma unroll
      for (int i = 0; i < 8; ++i)
        #pragma unroll
        for (int j = 0; j < 4; ++j)
          acc[i][j] = fmaf(wv[i], svv[j], acc[i][j]);
    }
    __syncthreads();   // protect s_w / s_samp for next chunk
  }

  // ---------------- Epilogue: bias + store ----------------
  #pragma unroll
  for (int i = 0; i < 8; ++i) {
    const float bd = b_def[oc0 + i];
    float4 v;
    v.x = acc[i][0] + bd;
    v.y = acc[i][1] + bd;
    v.z = acc[i][2] + bd;
    v.w = acc[i][3] + bd;
    *(float4*)&out[(((size_t)b * COUT + (oc0 + i)) * HH + ho) * WW + p0] = v;
  }
}

extern "C" void kernel_launch(void* const* d_in, const int* in_sizes, int n_in,
                              void* d_out, int out_size, void* d_ws, size_t ws_size,
                              hipStream_t stream) {
  const float* x     = (const float*)d_in[0];
  const float* w_off = (const float*)d_in[1];
  const float* b_off = (const float*)d_in[2];
  const float* w_def = (const float*)d_in[3];
  const float* b_def = (const float*)d_in[4];
  float* out = (float*)d_out;

  dim3 grid(NB * HH);   // 512 blocks: one per (batch, output row)
  dim3 block(256);
  dcn_fused_kernel<<<grid, block, 0, stream>>>(x, w_off, b_off, w_def, b_def, out);
}

// Round 2
// 290.541 us; speedup vs baseline: 4.8805x; 4.8805x over previous
//
#include <hip/hip_runtime.h>
#include <math.h>

typedef __attribute__((ext_vector_type(8))) short bf16x8;
typedef __attribute__((ext_vector_type(4))) float f32x4;
typedef __attribute__((ext_vector_type(4))) int i32x4;

#define NB   8
#define CI   128
#define CO   128
#define H_   64
#define W_   64
#define KTOT 1152   // CI*9
#define KC   64     // K-chunk
#define NCH  18     // KTOT/KC
#define LW   72     // LDS row stride (bf16 elems): mult of 8 -> 16B-aligned rows

__device__ __forceinline__ unsigned short f2bf(float f) {
  union { float f; unsigned u; } v; v.f = f;
  unsigned r = v.u + 0x7FFF + ((v.u >> 16) & 1);   // RNE
  return (unsigned short)(r >> 16);
}

// ---------------- Kernel 0: weights -> bf16 in workspace ----------------
// wsA: [32][1152] (w_off rows 0..26, zero-pad 27..31). wsB: [128][1152] w_def.
__global__ void prep_kernel(const float* __restrict__ w_off,
                            const float* __restrict__ w_def,
                            unsigned short* __restrict__ wsA,
                            unsigned short* __restrict__ wsB) {
  int i = blockIdx.x * 256 + threadIdx.x;
  const int NA = 32 * KTOT;
  if (i < NA) {
    int row = i / KTOT;
    wsA[i] = (row < 27) ? f2bf(w_off[i]) : (unsigned short)0;
  } else {
    int j = i - NA;
    wsB[j] = f2bf(w_def[j]);
  }
}

// ---------------- Kernel 1: offset conv (27ch 3x3) via MFMA ----------------
// One block per (b, ho). M=32(pad27), N=64, K=1152. Writes offm[b][27][ho][wo]
// fp32 with bias added and mask channels (18..26) sigmoided.
__global__ __launch_bounds__(256, 2)
void offset_conv_kernel(const float* __restrict__ x,
                        const unsigned short* __restrict__ wA,
                        const float* __restrict__ b_off,
                        float* __restrict__ offm) {
  __shared__ __align__(16) unsigned short s_w[32 * LW];
  __shared__ __align__(16) unsigned short s_s[64 * LW];
  const int t = threadIdx.x;
  const int b  = blockIdx.x >> 6;
  const int ho = blockIdx.x & 63;
  const int lane = t & 63, wid = t >> 6;
  const int q = lane >> 4, li = lane & 15;
  const float* __restrict__ xb = x + (size_t)b * CI * H_ * W_;

  const int mt  = wid >> 1;        // 0..1 : which 16 output channels
  const int nt0 = (wid & 1) * 2;   // 0 or 2 : which pair of px tiles
  f32x4 acc0 = {0.f, 0.f, 0.f, 0.f};
  f32x4 acc1 = {0.f, 0.f, 0.f, 0.f};

  for (int ch = 0; ch < NCH; ++ch) {
    const int k0 = ch * KC;
    __syncthreads();
    { // stage W chunk: 32 rows x 64 bf16 (8 bf16/thread)
      int row = t >> 3, ko = (t & 7) * 8;
      *(uint4*)&s_w[row * LW + ko] = *(const uint4*)&wA[row * KTOT + k0 + ko];
    }
    // im2col samples: s_s[px][ki], 4096 vals, 16/thread
    #pragma unroll 4
    for (int it = 0; it < 16; ++it) {
      int f  = t + it * 256;
      int px = f & 63, ki = f >> 6;
      int kk = k0 + ki;
      int cc = kk / 9;
      int k  = kk - cc * 9;
      int ky = k / 3, kx = k - ky * 3;
      int y  = ho + ky - 1, xx = px + kx - 1;
      float v = 0.f;
      if ((unsigned)y < 64u && (unsigned)xx < 64u) v = xb[(cc * 64 + y) * 64 + xx];
      s_s[px * LW + ki] = f2bf(v);
    }
    __syncthreads();
    #pragma unroll
    for (int ks = 0; ks < 2; ++ks) {
      const int kc = ks * 32 + q * 8;
      bf16x8 a  = *(const bf16x8*)&s_w[(mt * 16 + li) * LW + kc];
      bf16x8 b0 = *(const bf16x8*)&s_s[((nt0    ) * 16 + li) * LW + kc];
      bf16x8 b1 = *(const bf16x8*)&s_s[((nt0 + 1) * 16 + li) * LW + kc];
      acc0 = __builtin_amdgcn_mfma_f32_16x16x32_bf16(a, b0, acc0, 0, 0, 0);
      acc1 = __builtin_amdgcn_mfma_f32_16x16x32_bf16(a, b1, acc1, 0, 0, 0);
    }
  }
  // epilogue: D layout col=lane&15, row=q*4+r
  #pragma unroll
  for (int j = 0; j < 2; ++j) {
    f32x4 a = j ? acc1 : acc0;
    int px = (nt0 + j) * 16 + li;
    #pragma unroll
    for (int r = 0; r < 4; ++r) {
      int oc = mt * 16 + q * 4 + r;
      if (oc < 27) {
        float v = a[r] + b_off[oc];
        if (oc >= 18) v = 1.f / (1.f + __expf(-v));  // sigmoid (mask channels)
        offm[((b * 27 + oc) * 64 + ho) * 64 + px] = v;
      }
    }
  }
}

// ---------------- Kernel 2: DCNv2 via MFMA ----------------
// One block per (b, ho). M=128 oc, N=64 px, K=1152.
__global__ __launch_bounds__(256, 2)
void dcn_mfma_kernel(const float* __restrict__ x,
                     const unsigned short* __restrict__ wB,
                     const float* __restrict__ offm,
                     const float* __restrict__ b_def,
                     float* __restrict__ out) {
  __shared__ __align__(16) unsigned short s_w[128 * LW];  // 18432 B
  __shared__ __align__(16) unsigned short s_s[64 * LW];   //  9216 B
  __shared__ i32x4 s_idx[9 * 64];                         //  9216 B
  __shared__ f32x4 s_wt [9 * 64];                         //  9216 B
  const int t = threadIdx.x;
  const int b  = blockIdx.x >> 6;
  const int ho = blockIdx.x & 63;
  const int lane = t & 63, wid = t >> 6;
  const int q = lane >> 4, li = lane & 15;
  const float* __restrict__ xb = x + (size_t)b * CI * H_ * W_;
  const float* __restrict__ ob = offm + (size_t)b * 27 * 4096 + ho * 64;

  // Per-(k,px) bilinear corner indices + mask-premultiplied weights (ci-invariant)
  for (int f = t; f < 576; f += 256) {
    int k = f >> 6, px = f & 63;
    int ky = k / 3, kx = k - ky * 3;
    float offy = ob[(2 * k    ) * 4096 + px];
    float offx = ob[(2 * k + 1) * 4096 + px];
    float m    = ob[(18 + k   ) * 4096 + px];
    float py  = offy + (float)(ho + ky - 1);
    float pxf = offx + (float)(px + kx - 1);
    float y0f = floorf(py), x0f = floorf(pxf);
    float wy = py - y0f, wx = pxf - x0f;
    int y0 = (int)y0f, x0 = (int)x0f;
    int y1 = y0 + 1, x1 = x0 + 1;
    bool y0v = (unsigned)y0 < 64u, y1v = (unsigned)y1 < 64u;
    bool x0v = (unsigned)x0 < 64u, x1v = (unsigned)x1 < 64u;
    int y0c = min(max(y0, 0), 63), y1c = min(max(y1, 0), 63);
    int x0c = min(max(x0, 0), 63), x1c = min(max(x1, 0), 63);
    i32x4 ii; ii[0] = y0c * 64 + x0c; ii[1] = y0c * 64 + x1c;
              ii[2] = y1c * 64 + x0c; ii[3] = y1c * 64 + x1c;
    f32x4 wv;
    wv[0] = (y0v && x0v) ? (1.f - wy) * (1.f - wx) * m : 0.f;
    wv[1] = (y0v && x1v) ? (1.f - wy) * wx         * m : 0.f;
    wv[2] = (y1v && x0v) ? wy         * (1.f - wx) * m : 0.f;
    wv[3] = (y1v && x1v) ? wy         * wx         * m : 0.f;
    s_idx[f] = ii;
    s_wt[f]  = wv;
  }

  f32x4 acc[2][4];
  #pragma unroll
  for (int i = 0; i < 2; ++i)
    #pragma unroll
    for (int j = 0; j < 4; ++j) acc[i][j] = (f32x4){0.f, 0.f, 0.f, 0.f};

  for (int ch = 0; ch < NCH; ++ch) {
    const int k0 = ch * KC;
    __syncthreads();   // also covers table->sampling on first iter
    // stage W chunk: 128 rows x 64 bf16 (4 x 8 bf16/thread)
    #pragma unroll
    for (int it = 0; it < 4; ++it) {
      int slot = t + it * 256;
      int row = slot >> 3, ko = (slot & 7) * 8;
      *(uint4*)&s_w[row * LW + ko] = *(const uint4*)&wB[row * KTOT + k0 + ko];
    }
    // modulated bilinear samples: s_s[px][ki]
    #pragma unroll 4
    for (int it = 0; it < 16; ++it) {
      int f  = t + it * 256;
      int px = f & 63, ki = f >> 6;
      int kk = k0 + ki;
      int cc = kk / 9;
      int k  = kk - cc * 9;
      i32x4 ii = s_idx[k * 64 + px];
      f32x4 wv = s_wt [k * 64 + px];
      const float* __restrict__ xc = xb + cc * 4096;
      float v = wv[0] * xc[ii[0]] + wv[1] * xc[ii[1]] +
                wv[2] * xc[ii[2]] + wv[3] * xc[ii[3]];
      s_s[px * LW + ki] = f2bf(v);
    }
    __syncthreads();
    #pragma unroll
    for (int ks = 0; ks < 2; ++ks) {
      const int kc = ks * 32 + q * 8;
      bf16x8 a0 = *(const bf16x8*)&s_w[(wid * 32      + li) * LW + kc];
      bf16x8 a1 = *(const bf16x8*)&s_w[(wid * 32 + 16 + li) * LW + kc];
      #pragma unroll
      for (int nt = 0; nt < 4; ++nt) {
        bf16x8 bb = *(const bf16x8*)&s_s[(nt * 16 + li) * LW + kc];
        acc[0][nt] = __builtin_amdgcn_mfma_f32_16x16x32_bf16(a0, bb, acc[0][nt], 0, 0, 0);
        acc[1][nt] = __builtin_amdgcn_mfma_f32_16x16x32_bf16(a1, bb, acc[1][nt], 0, 0, 0);
      }
    }
  }

  // epilogue: oc = wid*32 + mt*16 + q*4 + r ; px = nt*16 + li
  #pragma unroll
  for (int mt = 0; mt < 2; ++mt) {
    #pragma unroll
    for (int r = 0; r < 4; ++r) {
      int oc = wid * 32 + mt * 16 + q * 4 + r;
      float bd = b_def[oc];
      float* orow = out + (((size_t)b * CO + oc) * 64 + ho) * 64;
      #pragma unroll
      for (int nt = 0; nt < 4; ++nt)
        orow[nt * 16 + li] = acc[mt][nt][r] + bd;
    }
  }
}

extern "C" void kernel_launch(void* const* d_in, const int* in_sizes, int n_in,
                              void* d_out, int out_size, void* d_ws, size_t ws_size,
                              hipStream_t stream) {
  const float* x     = (const float*)d_in[0];
  const float* w_off = (const float*)d_in[1];
  const float* b_off = (const float*)d_in[2];
  const float* w_def = (const float*)d_in[3];
  const float* b_def = (const float*)d_in[4];
  float* out = (float*)d_out;

  unsigned short* wsA = (unsigned short*)d_ws;              // 32*1152 bf16
  unsigned short* wsB = wsA + 32 * KTOT;                    // 128*1152 bf16
  float* offm = (float*)((char*)d_ws + 2 * (32 + 128) * KTOT); // 8*27*64*64 f32

  prep_kernel<<<dim3((32 + 128) * KTOT / 256), dim3(256), 0, stream>>>(w_off, w_def, wsA, wsB);
  offset_conv_kernel<<<dim3(NB * H_), dim3(256), 0, stream>>>(x, wsA, b_off, offm);
  dcn_mfma_kernel<<<dim3(NB * H_), dim3(256), 0, stream>>>(x, wsB, offm, b_def, out);
}